// Round 5
// baseline (225.819 us; speedup 1.0000x reference)
//
#include <hip/hip_runtime.h>
#include <hip/hip_bf16.h>

#define TRAJ 50

typedef __attribute__((ext_vector_type(8))) short short8;
typedef __attribute__((ext_vector_type(4))) float f32x4;
typedef __attribute__((ext_vector_type(2))) float f32x2;

__device__ __forceinline__ unsigned short f2bf(float f){
  union { float f; unsigned u; } v; v.f = f;
  unsigned u = v.u;
  u += 0x7FFFu + ((u >> 16) & 1u);   // RNE
  return (unsigned short)(u >> 16);
}
__device__ __forceinline__ unsigned pk(unsigned short a, unsigned short b){
  return (unsigned)a | ((unsigned)b << 16);
}
__device__ __forceinline__ unsigned pkbf(float a, float b){
  union { __hip_bfloat162 h; unsigned u; } c;
  c.h = __float22bfloat162_rn(make_float2(a, b));   // v_cvt_pk_bf16_f32
  return c.u;
}
__device__ __forceinline__ short8 mkfrag(uint2 v){
  union { unsigned u[4]; short8 s; } c;
  c.u[0] = v.x; c.u[1] = v.y; c.u[2] = 0u; c.u[3] = 0u;
  return c.s;
}

#define MFMA16(A,B,C) __builtin_amdgcn_mfma_f32_16x16x32_bf16((A),(B),(C),0,0,0)

#define SSC (-1.44269504f)   // sigmoid scale: sigma(x) = 1/(1+2^(SSC*x))
#define TSC ( 2.88539008f)   // tanh scale:   tanh(y)  = 1-2/(1+2^(TSC*y))

// ---- trans-free exp2: RNE split via magic add, deg-4 Taylor (rel err <= 4e-5),
// exponent reattached by integer add. Pure VALU, 2-wide packable. Valid |t| < ~120.
__device__ __forceinline__ f32x2 exp2fast(f32x2 t){
  const f32x2 C2 = (f32x2){12582912.f, 12582912.f};   // 1.5*2^23
  f32x2 fn = t + C2;                                  // RNE(t) encoded in mantissa
  f32x2 f  = t - (fn - C2);                           // f in [-0.5, 0.5]
  // 2^f = 1 + f*(L1 + f*(L2 + f*(L3 + f*L4)))
  f32x2 p = (f32x2){0.00961813f, 0.00961813f};
  p = __builtin_elementwise_fma(p, f, (f32x2){0.05550411f, 0.05550411f});
  p = __builtin_elementwise_fma(p, f, (f32x2){0.24022651f, 0.24022651f});
  p = __builtin_elementwise_fma(p, f, (f32x2){0.69314718f, 0.69314718f});
  p = __builtin_elementwise_fma(p, f, (f32x2){1.f, 1.f});
  union { f32x2 v; uint2 u; } pf, fu; pf.v = p; fu.v = fn;
  pf.u.x += (fu.u.x << 23);                           // *2^n (low bits of fn = n+bias junk; <<23 isolates n)
  pf.u.y += (fu.u.y << 23);
  return pf.v;
}
// ---- trans-free reciprocal: magic seed + 2 Newton steps (rel err <= 1e-5). d >= 1 here.
__device__ __forceinline__ f32x2 rcp_nr2(f32x2 d){
  union { f32x2 f; uint2 u; } c; c.f = d;
  c.u.x = 0x7EF127EAu - c.u.x;
  c.u.y = 0x7EF127EAu - c.u.y;
  f32x2 y = c.f;
  y = y * ((f32x2){2.f,2.f} - d * y);
  y = y * ((f32x2){2.f,2.f} - d * y);
  return y;
}
__device__ __forceinline__ float rcp_nr2s(float d){
  union { float f; unsigned u; } c; c.f = d;
  c.u = 0x7EF127EAu - c.u;
  float y = c.f;
  y = y * (2.f - d * y);
  y = y * (2.f - d * y);
  return y;
}

// 4 h-elements (two packed pairs). Shared rcp: one per 4 sigmoids, one per 2 tanh.
// Exact algebra vs per-element form; denominators in [1, 2^92] -> no overflow.
__device__ __forceinline__ void gru_quad(f32x4 aR, f32x4 aU, f32x4 aN, f32x4 aI,
                                         f32x2& hlo, f32x2& hhi){
  const f32x2 one = (f32x2){1.f, 1.f};
  f32x2 dRlo = exp2fast((f32x2){aR[0], aR[1]}) + one;
  f32x2 dRhi = exp2fast((f32x2){aR[2], aR[3]}) + one;
  f32x2 dUlo = exp2fast((f32x2){aU[0], aU[1]}) + one;
  f32x2 dUhi = exp2fast((f32x2){aU[2], aU[3]}) + one;
  f32x2 Glo = dRlo * dUlo, Ghi = dRhi * dUhi;
  f32x2 PQ = (f32x2){Glo[0] * Glo[1], Ghi[0] * Ghi[1]};
  f32x2 rp = rcp_nr2(PQ);
  f32x2 Slo = (f32x2){Glo[1], Glo[0]} * (f32x2){rp[0], rp[0]};
  f32x2 Shi = (f32x2){Ghi[1], Ghi[0]} * (f32x2){rp[1], rp[1]};
  f32x2 rvlo = dUlo * Slo, rvhi = dUhi * Shi;   // sigma(arg_r)
  f32x2 uvlo = dRlo * Slo, uvhi = dRhi * Shi;   // sigma(arg_u)
  f32x2 ylo = __builtin_elementwise_fma(rvlo, (f32x2){aN[0], aN[1]}, (f32x2){aI[0], aI[1]});
  f32x2 yhi = __builtin_elementwise_fma(rvhi, (f32x2){aN[2], aN[3]}, (f32x2){aI[2], aI[3]});
  f32x2 dNlo = exp2fast(ylo) + one;
  f32x2 dNhi = exp2fast(yhi) + one;
  f32x2 M = (f32x2){dNlo[0] * dNlo[1], dNhi[0] * dNhi[1]};
  f32x2 rp3 = rcp_nr2(M);
  f32x2 wlo = (f32x2){dNlo[1], dNlo[0]} * (f32x2){rp3[0], rp3[0]};
  f32x2 whi = (f32x2){dNhi[1], dNhi[0]} * (f32x2){rp3[1], rp3[1]};
  f32x2 nvlo = __builtin_elementwise_fma(wlo, (f32x2){-2.f,-2.f}, one);  // tanh
  f32x2 nvhi = __builtin_elementwise_fma(whi, (f32x2){-2.f,-2.f}, one);
  hlo = __builtin_elementwise_fma(uvlo, hlo - nvlo, nvlo);
  hhi = __builtin_elementwise_fma(uvhi, hhi - nvhi, nvhi);
}

// Block = 512 threads = 8 waves = 4 pairs; each pair owns 16 rows; wave p of a
// pair computes gate dims [32p, 32p+32). h exchanged via double-buffered LDS,
// one __syncthreads per rollout step. Gates computed as gates^T = A_aug @ h_B.
__global__ __launch_bounds__(512, 4) void gru_actor_kernel(
    const float* __restrict__ x,
    const float* __restrict__ W1, const float* __restrict__ b1,
    const float* __restrict__ W2, const float* __restrict__ b2,
    const float* __restrict__ Wih, const float* __restrict__ bih,
    const float* __restrict__ Whh, const float* __restrict__ bhh,
    const float* __restrict__ Wout, const float* __restrict__ bout,
    float* __restrict__ out)
{
  __shared__ __align__(16) char sm_x[32768];   // x tile [64][512B]; rollout: h0=+0, h1=+8192
  __shared__ __align__(16) char sm_w[32768];   // W1T full [64][512B] -> WhhT [192][128B] (pre-scaled)
  __shared__ __align__(16) char sm_w2[8192];   // W2T [64][128B]
  __shared__ float sm_b1[64];
  __shared__ float sm_b2[64];

  const int t    = threadIdx.x;        // 0..511
  const int row0 = blockIdx.x * 64;
  const int w    = t >> 6;             // wave 0..7
  const int pair = w >> 1;             // 0..3
  const int p    = w & 1;              // dim-half of the pair
  const int l    = t & 63;
  const int lr   = l & 15;
  const int lg   = l >> 4;
  const int myrow = pair * 16 + lr;    // 0..63
  const int swz  = (lr & 7) << 4;      // (myrow&7)==(lr&7); also == A-row swizzle

  // ---------------- stage x (f32 -> bf16, [64][512B] swizzled) ----------------
  {
    const float4* xg = (const float4*)(x + (size_t)row0 * 256);
    #pragma unroll
    for (int it = 0; it < 8; ++it){
      int fi = t + it * 512;
      float4 v = xg[fi];
      int e = fi * 4, row = e >> 8, col = e & 255;
      *(uint2*)(sm_x + row * 512 + ((col * 2) ^ ((row & 7) << 4))) =
          make_uint2(pkbf(v.x, v.y), pkbf(v.z, v.w));
    }
  }
  // W1T full: [i<64][k<256] bf16, stride 512B
  for (int n = t; n < 16384; n += 512){
    int i = n & 63, kk = n >> 6;
    *(unsigned short*)(sm_w + i * 512 + ((kk * 2) ^ ((i & 7) << 4))) = f2bf(W1[kk * 64 + i]);
  }
  // W2T: [64][64] bf16, stride 128B
  for (int n = t; n < 4096; n += 512){
    int i = n & 63, kk = n >> 6;
    *(unsigned short*)(sm_w2 + i * 128 + ((kk * 2) ^ ((i & 7) << 4))) = f2bf(W2[kk * 64 + i]);
  }
  if (t < 64){ sm_b1[t] = b1[t]; sm_b2[t] = b2[t]; }
  __syncthreads();                                   // B1: staging done

  // ---------------- layer 1: z1^T = relu(W1T @ xT + b1), wave does tiles 2p,2p+1 ----------------
  const int ar0 = 16 * (2 * p + 0) + lr;   // W-row for tile a  ((ar&7)==(lr&7))
  const int ar1 = 16 * (2 * p + 1) + lr;
  f32x4 accL0, accL1;
  {
    float4 bva = *(const float4*)(sm_b1 + 16 * (2 * p + 0) + lg * 4);
    float4 bvb = *(const float4*)(sm_b1 + 16 * (2 * p + 1) + lg * 4);
    accL0 = (f32x4){bva.x, bva.y, bva.z, bva.w};
    accL1 = (f32x4){bvb.x, bvb.y, bvb.z, bvb.w};
  }
  #pragma unroll
  for (int kb = 0; kb < 8; ++kb){
    short8 B  = *(const short8*)(sm_x + myrow * 512 + ((kb * 64 + lg * 16) ^ swz));
    short8 Aa = *(const short8*)(sm_w + ar0 * 512 + ((kb * 64 + lg * 16) ^ swz));
    short8 Ab = *(const short8*)(sm_w + ar1 * 512 + ((kb * 64 + lg * 16) ^ swz));
    accL0 = MFMA16(Aa, B, accL0);
    accL1 = MFMA16(Ab, B, accL1);
  }
  __syncthreads();                                   // B2: all x/W1T reads done

  // write z1 (bf16) into h0 region (aliases x tile); stage WhhT (aliases W1T, pre-scaled)
  {
    f32x4 a0 = accL0, a1 = accL1;
    *(uint2*)(sm_x + myrow * 128 + ((64 * p + 0  + 8 * lg) ^ swz)) =
        make_uint2(pkbf(fmaxf(a0[0],0.f), fmaxf(a0[1],0.f)), pkbf(fmaxf(a0[2],0.f), fmaxf(a0[3],0.f)));
    *(uint2*)(sm_x + myrow * 128 + ((64 * p + 32 + 8 * lg) ^ swz)) =
        make_uint2(pkbf(fmaxf(a1[0],0.f), fmaxf(a1[1],0.f)), pkbf(fmaxf(a1[2],0.f), fmaxf(a1[3],0.f)));
  }
  for (int n = t; n < 12288; n += 512){
    int kk = n / 192, i = n - kk * 192;
    float s = (i < 128) ? SSC : TSC;   // r,u rows scaled by SSC; n rows by TSC
    *(unsigned short*)(sm_w + i * 128 + ((kk * 2) ^ ((i & 7) << 4))) = f2bf(s * Whh[kk * 192 + i]);
  }
  __syncthreads();                                   // B3: z1 + WhhT ready

  // ---------------- layer 2: h = relu(W2T @ z1T + b2) ----------------
  f32x2 h2[4];
  {
    f32x4 acc20, acc21;
    float4 bva = *(const float4*)(sm_b2 + 16 * (2 * p + 0) + lg * 4);
    float4 bvb = *(const float4*)(sm_b2 + 16 * (2 * p + 1) + lg * 4);
    acc20 = (f32x4){bva.x, bva.y, bva.z, bva.w};
    acc21 = (f32x4){bvb.x, bvb.y, bvb.z, bvb.w};
    #pragma unroll
    for (int kb = 0; kb < 2; ++kb){
      short8 B  = *(const short8*)(sm_x + myrow * 128 + ((kb * 64 + lg * 16) ^ swz));
      short8 Aa = *(const short8*)(sm_w2 + ar0 * 128 + ((kb * 64 + lg * 16) ^ swz));
      short8 Ab = *(const short8*)(sm_w2 + ar1 * 128 + ((kb * 64 + lg * 16) ^ swz));
      acc20 = MFMA16(Aa, B, acc20);
      acc21 = MFMA16(Ab, B, acc21);
    }
    h2[0] = (f32x2){fmaxf(acc20[0],0.f), fmaxf(acc20[1],0.f)};
    h2[1] = (f32x2){fmaxf(acc20[2],0.f), fmaxf(acc20[3],0.f)};
    h2[2] = (f32x2){fmaxf(acc21[0],0.f), fmaxf(acc21[1],0.f)};
    h2[3] = (f32x2){fmaxf(acc21[2],0.f), fmaxf(acc21[3],0.f)};
    *(uint2*)(sm_x + 8192 + myrow * 128 + ((64 * p + 0  + 8 * lg) ^ swz)) =
        make_uint2(pkbf(h2[0][0], h2[0][1]), pkbf(h2[1][0], h2[1][1]));
    *(uint2*)(sm_x + 8192 + myrow * 128 + ((64 * p + 32 + 8 * lg) ^ swz)) =
        make_uint2(pkbf(h2[2][0], h2[2][1]), pkbf(h2[3][0], h2[3][1]));
  }

  // ---------------- preload loop-invariant fragments ----------------
  short8 Ah[3][2][2];    // [gate r/u/n][tql][kb]: WhhT rows (pre-scaled)
  #pragma unroll
  for (int g = 0; g < 3; ++g){
    #pragma unroll
    for (int tql = 0; tql < 2; ++tql){
      int i = g * 64 + 32 * p + 16 * tql + lr;
      #pragma unroll
      for (int kb = 0; kb < 2; ++kb)
        Ah[g][tql][kb] = *(const short8*)(sm_w + i * 128 + ((kb * 64 + lg * 16) ^ swz));
    }
  }
  // augmented k-block (k=64:wp0, 65:wp1, 66:1.0) -> only lg==0 lanes nonzero; packed uint2
  uint2 Ak2p[4][2] = {};   // [r,u,hn,inn][tql]
  if (lg == 0){
    #pragma unroll
    for (int tql = 0; tql < 2; ++tql){
      int dr = 32 * p + 16 * tql + lr;
      int du = 64 + dr, dn = 128 + dr;
      Ak2p[0][tql] = make_uint2(pk(f2bf(SSC*Wih[dr]), f2bf(SSC*Wih[192+dr])),
                                pk(f2bf(SSC*(bih[dr]+bhh[dr])), 0));
      Ak2p[1][tql] = make_uint2(pk(f2bf(SSC*Wih[du]), f2bf(SSC*Wih[192+du])),
                                pk(f2bf(SSC*(bih[du]+bhh[du])), 0));
      Ak2p[2][tql] = make_uint2(0u, pk(f2bf(TSC*bhh[dn]), 0));
      Ak2p[3][tql] = make_uint2(pk(f2bf(TSC*Wih[dn]), f2bf(TSC*Wih[192+dn])),
                                pk(f2bf(TSC*bih[dn]), 0));
    }
  }
  // Wout^T fragments in REGISTERS (loop-invariant)
  short8 AoR[2];
  #pragma unroll
  for (int kb = 0; kb < 2; ++kb){
    short8 f = (short8){0,0,0,0,0,0,0,0};
    if (lr < 2){
      #pragma unroll
      for (int j = 0; j < 8; ++j){
        int k = kb * 32 + lg * 8 + j;
        f[j] = (short)f2bf(SSC * Wout[k * 2 + lr]);
      }
    }
    AoR[kb] = f;
  }
  const float bo0 = SSC * bout[0], bo1 = SSC * bout[1];
  __syncthreads();                                   // B4: h(buf1) ready

  // ---------------- GRU rollout: 1 barrier/step, h double-buffered ----------------
  float wp0 = 0.f, wp1 = 0.f;
  float* outp = out + (size_t)(row0 + myrow) * 100;
  short8 B0 = *(const short8*)(sm_x + 8192 + myrow * 128 + ((0  + lg * 16) ^ swz));
  short8 B1 = *(const short8*)(sm_x + 8192 + myrow * 128 + ((64 + lg * 16) ^ swz));

  #pragma unroll 2
  for (int s = 0; s < TRAJ; ++s){
    char* bufW = sm_x + ((s & 1) << 13);   // step0 writes h0, step1 h1, ...
    short8 B2;
    {
      unsigned b2lo = 0u, b2hi = 0u;
      if (lg == 0){ b2lo = pkbf(wp0, wp1); b2hi = 0x00003F80u; }   // f[2] = 1.0bf
      union { unsigned u[4]; short8 sv; } c;
      c.u[0] = b2lo; c.u[1] = b2hi; c.u[2] = 0u; c.u[3] = 0u;
      B2 = c.sv;
    }
    #pragma unroll
    for (int tql = 0; tql < 2; ++tql){
      f32x4 aR = (f32x4){0,0,0,0}, aU = (f32x4){0,0,0,0};
      f32x4 aN = (f32x4){0,0,0,0}, aI = (f32x4){0,0,0,0};
      aR = MFMA16(Ah[0][tql][0], B0, aR);
      aR = MFMA16(Ah[0][tql][1], B1, aR);
      aR = MFMA16(mkfrag(Ak2p[0][tql]), B2, aR);
      aU = MFMA16(Ah[1][tql][0], B0, aU);
      aU = MFMA16(Ah[1][tql][1], B1, aU);
      aU = MFMA16(mkfrag(Ak2p[1][tql]), B2, aU);
      aN = MFMA16(Ah[2][tql][0], B0, aN);
      aN = MFMA16(Ah[2][tql][1], B1, aN);
      aN = MFMA16(mkfrag(Ak2p[2][tql]), B2, aN);
      aI = MFMA16(mkfrag(Ak2p[3][tql]), B2, aI);
      gru_quad(aR, aU, aN, aI, h2[2*tql+0], h2[2*tql+1]);
      *(uint2*)(bufW + myrow * 128 + ((64 * p + 32 * tql + 8 * lg) ^ swz)) =
          make_uint2(pkbf(h2[2*tql+0][0], h2[2*tql+0][1]), pkbf(h2[2*tql+1][0], h2[2*tql+1][1]));
    }
    __syncthreads();
    short8 nB0 = *(const short8*)(bufW + myrow * 128 + ((0  + lg * 16) ^ swz));
    short8 nB1 = *(const short8*)(bufW + myrow * 128 + ((64 + lg * 16) ^ swz));
    f32x4 aD = (f32x4){0,0,0,0};
    if (lg == 0){ aD[0] = bo0; aD[1] = bo1; }
    aD = MFMA16(AoR[0], nB0, aD);
    aD = MFMA16(AoR[1], nB1, aD);
    {
      // sigmoid pair via trans-free exp2 + shared Newton rcp (all lanes; only lg==0 meaningful)
      const f32x2 one = (f32x2){1.f, 1.f};
      f32x2 dD = exp2fast((f32x2){aD[0], aD[1]}) + one;
      float rpD = rcp_nr2s(dD[0] * dD[1]);
      wp0 += dD[1] * rpD;                      // sigmoid(dx0)
      wp1 += dD[0] * rpD;                      // sigmoid(dx1)
    }
    if (lg == 0 && p == 0)
      *(float2*)(outp + 2 * s) = make_float2(wp0, wp1);
    B0 = nB0; B1 = nB1;
  }
}

extern "C" void kernel_launch(void* const* d_in, const int* in_sizes, int n_in,
                              void* d_out, int out_size, void* d_ws, size_t ws_size,
                              hipStream_t stream) {
  (void)n_in; (void)out_size; (void)d_ws; (void)ws_size;
  const float* x    = (const float*)d_in[0];
  const float* W1   = (const float*)d_in[1];
  const float* b1   = (const float*)d_in[2];
  const float* W2   = (const float*)d_in[3];
  const float* b2   = (const float*)d_in[4];
  const float* Wih  = (const float*)d_in[5];
  const float* bih  = (const float*)d_in[6];
  const float* Whh  = (const float*)d_in[7];
  const float* bhh  = (const float*)d_in[8];
  const float* Wout = (const float*)d_in[9];
  const float* bout = (const float*)d_in[10];
  float* out = (float*)d_out;

  int nrows = in_sizes[0] / 256;
  int grid  = nrows / 64;
  gru_actor_kernel<<<dim3(grid), dim3(512), 0, stream>>>(
      x, W1, b1, W2, b2, Wih, bih, Whh, bhh, Wout, bout, out);
}

// Round 6
// 118.863 us; speedup vs baseline: 1.8998x; 1.8998x over previous
//
#include <hip/hip_runtime.h>
#include <hip/hip_bf16.h>

#define TRAJ 50

typedef __attribute__((ext_vector_type(8))) short short8;
typedef __attribute__((ext_vector_type(4))) float f32x4;
typedef __attribute__((ext_vector_type(2))) float f32x2;

#if defined(__has_builtin)
#if __has_builtin(__builtin_amdgcn_exp2f)
#define EXP2F(x) __builtin_amdgcn_exp2f(x)
#else
#define EXP2F(x) exp2f(x)
#endif
#if __has_builtin(__builtin_amdgcn_rcpf)
#define RCPF(x) __builtin_amdgcn_rcpf(x)
#else
#define RCPF(x) (1.0f/(x))
#endif
#else
#define EXP2F(x) exp2f(x)
#define RCPF(x) (1.0f/(x))
#endif

// LDS-only barrier, FUSED into one asm block (round-3 fix: no schedulable gap
// between the lgkm wait and s_barrier). Waits LDS writes but NOT global stores,
// so the scattered per-step trajectory stores never serialize the rollout.
#define BAR() asm volatile("s_waitcnt lgkmcnt(0)\n\ts_barrier" ::: "memory")

__device__ __forceinline__ unsigned short f2bf(float f){
  union { float f; unsigned u; } v; v.f = f;
  unsigned u = v.u;
  u += 0x7FFFu + ((u >> 16) & 1u);   // RNE
  return (unsigned short)(u >> 16);
}
__device__ __forceinline__ unsigned pk(unsigned short a, unsigned short b){
  return (unsigned)a | ((unsigned)b << 16);
}
__device__ __forceinline__ unsigned pkbf(float a, float b){
  union { __hip_bfloat162 h; unsigned u; } c;
  c.h = __float22bfloat162_rn(make_float2(a, b));   // v_cvt_pk_bf16_f32
  return c.u;
}
__device__ __forceinline__ short8 mkfrag(uint2 v){
  union { unsigned u[4]; short8 s; } c;
  c.u[0] = v.x; c.u[1] = v.y; c.u[2] = 0u; c.u[3] = 0u;
  return c.s;
}

#define MFMA16(A,B,C) __builtin_amdgcn_mfma_f32_16x16x32_bf16((A),(B),(C),0,0,0)

#define SSC (-1.44269504f)   // sigmoid scale: sigma(x) = 1/(1+2^(SSC*x))
#define TSC ( 2.88539008f)   // tanh scale:   tanh(y)  = 1-2/(1+2^(TSC*y))

__device__ __forceinline__ f32x2 exp2v(f32x2 v){ return (f32x2){EXP2F(v[0]), EXP2F(v[1])}; }
__device__ __forceinline__ f32x2 rcpv (f32x2 v){ return (f32x2){RCPF(v[0]), RCPF(v[1])}; }

// per element pair: r/u sigmoids share one rcp; tanh via exp2+rcp.
// (round-2 math, verified absmax 0.125)
__device__ __forceinline__ f32x2 gru_pair(f32x2 r_, f32x2 u_, f32x2 n_, f32x2 i_, f32x2 hp){
  const f32x2 one = (f32x2){1.f, 1.f};
  f32x2 d1 = exp2v(r_) + one;
  f32x2 d2 = exp2v(u_) + one;
  f32x2 rp = rcpv(d1 * d2);
  f32x2 rv = d2 * rp;                               // sigma(arg_r)
  f32x2 uv = d1 * rp;                               // sigma(arg_u)
  f32x2 y  = __builtin_elementwise_fma(rv, n_, i_); // TSC*(inn + r*hn)
  f32x2 nv = one - 2.f * rcpv(exp2v(y) + one);      // tanh
  return __builtin_elementwise_fma(uv, hp - nv, nv);
}

// Block = 512 threads = 8 waves = 4 pairs; each pair owns 16 rows; wave p of a
// pair computes gate dims [32p, 32p+32). h exchanged via double-buffered LDS,
// one LDS-only fused barrier per rollout step. gates^T = A_aug @ h_B.
__global__ __launch_bounds__(512, 4) void gru_actor_kernel(
    const float* __restrict__ x,
    const float* __restrict__ W1, const float* __restrict__ b1,
    const float* __restrict__ W2, const float* __restrict__ b2,
    const float* __restrict__ Wih, const float* __restrict__ bih,
    const float* __restrict__ Whh, const float* __restrict__ bhh,
    const float* __restrict__ Wout, const float* __restrict__ bout,
    float* __restrict__ out)
{
  __shared__ __align__(16) char sm_x[32768];   // x tile [64][512B]; rollout: h0=+0, h1=+8192
  __shared__ __align__(16) char sm_w[32768];   // W1T full [64][512B] -> WhhT [192][128B] (pre-scaled)
  __shared__ __align__(16) char sm_w2[8192];   // W2T [64][128B]
  __shared__ float sm_b1[64];
  __shared__ float sm_b2[64];

  const int t    = threadIdx.x;        // 0..511
  const int row0 = blockIdx.x * 64;
  const int w    = t >> 6;             // wave 0..7
  const int pair = w >> 1;             // 0..3
  const int p    = w & 1;              // dim-half of the pair
  const int l    = t & 63;
  const int lr   = l & 15;
  const int lg   = l >> 4;
  const int myrow = pair * 16 + lr;    // 0..63
  const int swz  = (lr & 7) << 4;      // (myrow&7)==(lr&7); also == A-row swizzle

  // ---------------- stage x (f32 -> bf16, [64][512B] swizzled) ----------------
  {
    const float4* xg = (const float4*)(x + (size_t)row0 * 256);
    #pragma unroll
    for (int it = 0; it < 8; ++it){
      int fi = t + it * 512;
      float4 v = xg[fi];
      int e = fi * 4, row = e >> 8, col = e & 255;
      *(uint2*)(sm_x + row * 512 + ((col * 2) ^ ((row & 7) << 4))) =
          make_uint2(pkbf(v.x, v.y), pkbf(v.z, v.w));
    }
  }
  // W1T full: [i<64][k<256] bf16, stride 512B
  for (int n = t; n < 16384; n += 512){
    int i = n & 63, kk = n >> 6;
    *(unsigned short*)(sm_w + i * 512 + ((kk * 2) ^ ((i & 7) << 4))) = f2bf(W1[kk * 64 + i]);
  }
  // W2T: [64][64] bf16, stride 128B
  for (int n = t; n < 4096; n += 512){
    int i = n & 63, kk = n >> 6;
    *(unsigned short*)(sm_w2 + i * 128 + ((kk * 2) ^ ((i & 7) << 4))) = f2bf(W2[kk * 64 + i]);
  }
  if (t < 64){ sm_b1[t] = b1[t]; sm_b2[t] = b2[t]; }
  __syncthreads();                                   // B1: staging done

  // ---------------- layer 1: z1^T = relu(W1T @ xT + b1), wave does tiles 2p,2p+1 ----------------
  const int ar0 = 16 * (2 * p + 0) + lr;   // W-row for tile a  ((ar&7)==(lr&7))
  const int ar1 = 16 * (2 * p + 1) + lr;
  f32x4 accL0, accL1;
  {
    float4 bva = *(const float4*)(sm_b1 + 16 * (2 * p + 0) + lg * 4);
    float4 bvb = *(const float4*)(sm_b1 + 16 * (2 * p + 1) + lg * 4);
    accL0 = (f32x4){bva.x, bva.y, bva.z, bva.w};
    accL1 = (f32x4){bvb.x, bvb.y, bvb.z, bvb.w};
  }
  #pragma unroll
  for (int kb = 0; kb < 8; ++kb){
    short8 B  = *(const short8*)(sm_x + myrow * 512 + ((kb * 64 + lg * 16) ^ swz));
    short8 Aa = *(const short8*)(sm_w + ar0 * 512 + ((kb * 64 + lg * 16) ^ swz));
    short8 Ab = *(const short8*)(sm_w + ar1 * 512 + ((kb * 64 + lg * 16) ^ swz));
    accL0 = MFMA16(Aa, B, accL0);
    accL1 = MFMA16(Ab, B, accL1);
  }
  __syncthreads();                                   // B2: all x/W1T reads done

  // write z1 (bf16) into h0 region (aliases x tile); stage WhhT (aliases W1T, pre-scaled)
  {
    f32x4 a0 = accL0, a1 = accL1;
    *(uint2*)(sm_x + myrow * 128 + ((64 * p + 0  + 8 * lg) ^ swz)) =
        make_uint2(pkbf(fmaxf(a0[0],0.f), fmaxf(a0[1],0.f)), pkbf(fmaxf(a0[2],0.f), fmaxf(a0[3],0.f)));
    *(uint2*)(sm_x + myrow * 128 + ((64 * p + 32 + 8 * lg) ^ swz)) =
        make_uint2(pkbf(fmaxf(a1[0],0.f), fmaxf(a1[1],0.f)), pkbf(fmaxf(a1[2],0.f), fmaxf(a1[3],0.f)));
  }
  for (int n = t; n < 12288; n += 512){
    int kk = n / 192, i = n - kk * 192;
    float s = (i < 128) ? SSC : TSC;   // r,u rows scaled by SSC; n rows by TSC
    *(unsigned short*)(sm_w + i * 128 + ((kk * 2) ^ ((i & 7) << 4))) = f2bf(s * Whh[kk * 192 + i]);
  }
  __syncthreads();                                   // B3: z1 + WhhT ready

  // ---------------- layer 2: h = relu(W2T @ z1T + b2) ----------------
  f32x2 h2[4];
  {
    f32x4 acc20, acc21;
    float4 bva = *(const float4*)(sm_b2 + 16 * (2 * p + 0) + lg * 4);
    float4 bvb = *(const float4*)(sm_b2 + 16 * (2 * p + 1) + lg * 4);
    acc20 = (f32x4){bva.x, bva.y, bva.z, bva.w};
    acc21 = (f32x4){bvb.x, bvb.y, bvb.z, bvb.w};
    #pragma unroll
    for (int kb = 0; kb < 2; ++kb){
      short8 B  = *(const short8*)(sm_x + myrow * 128 + ((kb * 64 + lg * 16) ^ swz));
      short8 Aa = *(const short8*)(sm_w2 + ar0 * 128 + ((kb * 64 + lg * 16) ^ swz));
      short8 Ab = *(const short8*)(sm_w2 + ar1 * 128 + ((kb * 64 + lg * 16) ^ swz));
      acc20 = MFMA16(Aa, B, acc20);
      acc21 = MFMA16(Ab, B, acc21);
    }
    h2[0] = (f32x2){fmaxf(acc20[0],0.f), fmaxf(acc20[1],0.f)};
    h2[1] = (f32x2){fmaxf(acc20[2],0.f), fmaxf(acc20[3],0.f)};
    h2[2] = (f32x2){fmaxf(acc21[0],0.f), fmaxf(acc21[1],0.f)};
    h2[3] = (f32x2){fmaxf(acc21[2],0.f), fmaxf(acc21[3],0.f)};
    *(uint2*)(sm_x + 8192 + myrow * 128 + ((64 * p + 0  + 8 * lg) ^ swz)) =
        make_uint2(pkbf(h2[0][0], h2[0][1]), pkbf(h2[1][0], h2[1][1]));
    *(uint2*)(sm_x + 8192 + myrow * 128 + ((64 * p + 32 + 8 * lg) ^ swz)) =
        make_uint2(pkbf(h2[2][0], h2[2][1]), pkbf(h2[3][0], h2[3][1]));
  }

  // ---------------- preload loop-invariant fragments ----------------
  short8 Ah[3][2][2];    // [gate r/u/n][tql][kb]: WhhT rows (pre-scaled)
  #pragma unroll
  for (int g = 0; g < 3; ++g){
    #pragma unroll
    for (int tql = 0; tql < 2; ++tql){
      int i = g * 64 + 32 * p + 16 * tql + lr;
      #pragma unroll
      for (int kb = 0; kb < 2; ++kb)
        Ah[g][tql][kb] = *(const short8*)(sm_w + i * 128 + ((kb * 64 + lg * 16) ^ swz));
    }
  }
  // augmented k-block (k=64:wp0, 65:wp1, 66:1.0) -> only lg==0 lanes nonzero; packed uint2
  uint2 Ak2p[4][2] = {};   // [r,u,hn,inn][tql]
  if (lg == 0){
    #pragma unroll
    for (int tql = 0; tql < 2; ++tql){
      int dr = 32 * p + 16 * tql + lr;
      int du = 64 + dr, dn = 128 + dr;
      Ak2p[0][tql] = make_uint2(pk(f2bf(SSC*Wih[dr]), f2bf(SSC*Wih[192+dr])),
                                pk(f2bf(SSC*(bih[dr]+bhh[dr])), 0));
      Ak2p[1][tql] = make_uint2(pk(f2bf(SSC*Wih[du]), f2bf(SSC*Wih[192+du])),
                                pk(f2bf(SSC*(bih[du]+bhh[du])), 0));
      Ak2p[2][tql] = make_uint2(0u, pk(f2bf(TSC*bhh[dn]), 0));
      Ak2p[3][tql] = make_uint2(pk(f2bf(TSC*Wih[dn]), f2bf(TSC*Wih[192+dn])),
                                pk(f2bf(TSC*bih[dn]), 0));
    }
  }
  // Wout^T fragments in REGISTERS (loop-invariant; kills the 16-way sm_wo conflict)
  short8 AoR[2];
  #pragma unroll
  for (int kb = 0; kb < 2; ++kb){
    short8 f = (short8){0,0,0,0,0,0,0,0};
    if (lr < 2){
      #pragma unroll
      for (int j = 0; j < 8; ++j){
        int k = kb * 32 + lg * 8 + j;
        f[j] = (short)f2bf(SSC * Wout[k * 2 + lr]);
      }
    }
    AoR[kb] = f;
  }
  const float bo0 = SSC * bout[0], bo1 = SSC * bout[1];
  __syncthreads();                                   // B4: h(buf1) ready

  // ---------------- GRU rollout: 1 fused LDS-barrier/step, h double-buffered ----------------
  float wp0 = 0.f, wp1 = 0.f;
  float* outp = out + (size_t)(row0 + myrow) * 100;
  short8 B0 = *(const short8*)(sm_x + 8192 + myrow * 128 + ((0  + lg * 16) ^ swz));
  short8 B1 = *(const short8*)(sm_x + 8192 + myrow * 128 + ((64 + lg * 16) ^ swz));

  #pragma unroll 2
  for (int s = 0; s < TRAJ; ++s){
    char* bufW = sm_x + ((s & 1) << 13);   // step0 writes h0, step1 h1, ...
    short8 B2;
    {
      unsigned b2lo = 0u, b2hi = 0u;
      if (lg == 0){ b2lo = pkbf(wp0, wp1); b2hi = 0x00003F80u; }   // f[2] = 1.0bf
      union { unsigned u[4]; short8 sv; } c;
      c.u[0] = b2lo; c.u[1] = b2hi; c.u[2] = 0u; c.u[3] = 0u;
      B2 = c.sv;
    }
    #pragma unroll
    for (int tql = 0; tql < 2; ++tql){
      f32x4 aR = (f32x4){0,0,0,0}, aU = (f32x4){0,0,0,0};
      f32x4 aN = (f32x4){0,0,0,0}, aI = (f32x4){0,0,0,0};
      aR = MFMA16(Ah[0][tql][0], B0, aR);
      aR = MFMA16(Ah[0][tql][1], B1, aR);
      aR = MFMA16(mkfrag(Ak2p[0][tql]), B2, aR);
      aU = MFMA16(Ah[1][tql][0], B0, aU);
      aU = MFMA16(Ah[1][tql][1], B1, aU);
      aU = MFMA16(mkfrag(Ak2p[1][tql]), B2, aU);
      aN = MFMA16(Ah[2][tql][0], B0, aN);
      aN = MFMA16(Ah[2][tql][1], B1, aN);
      aN = MFMA16(mkfrag(Ak2p[2][tql]), B2, aN);
      aI = MFMA16(mkfrag(Ak2p[3][tql]), B2, aI);
      f32x2 hA = gru_pair((f32x2){aR[0],aR[1]}, (f32x2){aU[0],aU[1]},
                          (f32x2){aN[0],aN[1]}, (f32x2){aI[0],aI[1]}, h2[2*tql+0]);
      f32x2 hB = gru_pair((f32x2){aR[2],aR[3]}, (f32x2){aU[2],aU[3]},
                          (f32x2){aN[2],aN[3]}, (f32x2){aI[2],aI[3]}, h2[2*tql+1]);
      h2[2*tql+0] = hA; h2[2*tql+1] = hB;
      *(uint2*)(bufW + myrow * 128 + ((64 * p + 32 * tql + 8 * lg) ^ swz)) =
          make_uint2(pkbf(hA[0], hA[1]), pkbf(hB[0], hB[1]));
    }
    BAR();                                     // fused lgkmcnt(0)+s_barrier (LDS-only)
    short8 nB0 = *(const short8*)(bufW + myrow * 128 + ((0  + lg * 16) ^ swz));
    short8 nB1 = *(const short8*)(bufW + myrow * 128 + ((64 + lg * 16) ^ swz));
    f32x4 aD = (f32x4){0,0,0,0};
    if (lg == 0){ aD[0] = bo0; aD[1] = bo1; }
    aD = MFMA16(AoR[0], nB0, aD);
    aD = MFMA16(AoR[1], nB1, aD);
    if (lg == 0){
      float ea = EXP2F(aD[0]), eb = EXP2F(aD[1]);
      float da = 1.f + ea, db = 1.f + eb;
      float rp = RCPF(da * db);
      wp0 += db * rp;                          // sigmoid(dx0)
      wp1 += da * rp;                          // sigmoid(dx1)
      if (p == 0) *(float2*)(outp + 2 * s) = make_float2(wp0, wp1);
    }
    B0 = nB0; B1 = nB1;
  }
}

extern "C" void kernel_launch(void* const* d_in, const int* in_sizes, int n_in,
                              void* d_out, int out_size, void* d_ws, size_t ws_size,
                              hipStream_t stream) {
  (void)n_in; (void)out_size; (void)d_ws; (void)ws_size;
  const float* x    = (const float*)d_in[0];
  const float* W1   = (const float*)d_in[1];
  const float* b1   = (const float*)d_in[2];
  const float* W2   = (const float*)d_in[3];
  const float* b2   = (const float*)d_in[4];
  const float* Wih  = (const float*)d_in[5];
  const float* bih  = (const float*)d_in[6];
  const float* Whh  = (const float*)d_in[7];
  const float* bhh  = (const float*)d_in[8];
  const float* Wout = (const float*)d_in[9];
  const float* bout = (const float*)d_in[10];
  float* out = (float*)d_out;

  int nrows = in_sizes[0] / 256;
  int grid  = nrows / 64;
  gru_actor_kernel<<<dim3(grid), dim3(512), 0, stream>>>(
      x, W1, b1, W2, b2, Wih, bih, Whh, bhh, Wout, bout, out);
}